// Round 1
// baseline (412.046 us; speedup 1.0000x reference)
//
#include <hip/hip_runtime.h>

#define D_MODEL 2048
#define ADAPTER 64
#define RPB     32          // rows per block
#define THREADS 256
#define NROWS   16384       // 4 * 4096

typedef __attribute__((ext_vector_type(4))) float f32x4;
typedef __attribute__((ext_vector_type(8))) short bf16x8;

__device__ __forceinline__ unsigned short f2bf(float f) {
    unsigned int u = __float_as_uint(f);
    u += 0x7fffu + ((u >> 16) & 1u);       // round-to-nearest-even
    return (unsigned short)(u >> 16);
}

__device__ __forceinline__ bf16x8 pack8(f32x4 a, f32x4 b) {
    bf16x8 r;
#pragma unroll
    for (int j = 0; j < 4; ++j) {
        r[j]     = (short)f2bf(a[j]);
        r[4 + j] = (short)f2bf(b[j]);
    }
    return r;
}

__global__ __launch_bounds__(THREADS, 2)
void houlsby_fused(const float* __restrict__ x,
                   const float* __restrict__ lnw,
                   const float* __restrict__ lnb,
                   const float* __restrict__ dw,   // [64][2048]
                   const float* __restrict__ db,   // [64]
                   const float* __restrict__ uw,   // [2048][64]
                   const float* __restrict__ ub,   // [2048]
                   float* __restrict__ out)
{
    __shared__ float stats_mu[RPB];
    __shared__ float stats_rs[RPB];
    __shared__ __align__(16) unsigned short Hl[RPB][ADAPTER + 8];  // bf16 bits, padded

    const int tid = threadIdx.x;
    const int w   = tid >> 6;      // wave 0..3
    const int l   = tid & 63;      // lane
    const int rowBase = blockIdx.x * RPB;

    // ---------- Phase 1: LayerNorm stats (8 rows per wave, coalesced) ----------
    for (int rr = 0; rr < 8; ++rr) {
        const int row = 8 * w + rr;
        const float* xr = x + (size_t)(rowBase + row) * D_MODEL;
        float s = 0.f, sq = 0.f;
#pragma unroll
        for (int j = 0; j < 8; ++j) {
            f32x4 v = *(const f32x4*)(xr + 4 * l + 256 * j);
            s  += v.x + v.y + v.z + v.w;
            sq += v.x * v.x + v.y * v.y + v.z * v.z + v.w * v.w;
        }
#pragma unroll
        for (int off = 32; off; off >>= 1) {
            s  += __shfl_xor(s,  off, 64);
            sq += __shfl_xor(sq, off, 64);
        }
        if (l == 0) {
            const float mu  = s * (1.f / D_MODEL);
            const float var = sq * (1.f / D_MODEL) - mu * mu;
            stats_mu[row] = mu;
            stats_rs[row] = rsqrtf(var + 1e-5f);
        }
    }
    __syncthreads();

    // ---------- Phase 2: down-proj GEMM (M=32 rows, N=64, K=2048), bf16 MFMA ----------
    const int rt = w & 1;          // row tile (16 rows each)
    const int ag = w >> 1;         // a-group: tiles {2ag, 2ag+1} -> a in [32ag, 32ag+32)
    const int m  = l & 15;
    const int g  = l >> 4;         // k-group

    const int lrow = 16 * rt + m;              // block-local token row for A frags
    const float mu  = stats_mu[lrow];
    const float rs  = stats_rs[lrow];
    const float nmr = -mu * rs;                // (x - mu)*rs == fma(x, rs, nmr)

    const float* xrow = x + (size_t)(rowBase + lrow) * D_MODEL;
    const int a0 = 32 * ag + m;
    const int a1 = a0 + 16;
    const float* dwr0 = dw + a0 * D_MODEL;
    const float* dwr1 = dw + a1 * D_MODEL;

    f32x4 acc0 = {0.f, 0.f, 0.f, 0.f};
    f32x4 acc1 = {0.f, 0.f, 0.f, 0.f};

    for (int ks = 0; ks < 64; ++ks) {
        const int kb = 32 * ks + 8 * g;
        f32x4 xv0 = *(const f32x4*)(xrow + kb);
        f32x4 xv1 = *(const f32x4*)(xrow + kb + 4);
        f32x4 lw0 = *(const f32x4*)(lnw + kb);
        f32x4 lw1 = *(const f32x4*)(lnw + kb + 4);
        f32x4 lb0 = *(const f32x4*)(lnb + kb);
        f32x4 lb1 = *(const f32x4*)(lnb + kb + 4);
        f32x4 v0, v1;
#pragma unroll
        for (int j = 0; j < 4; ++j) {
            v0[j] = fmaf(fmaf(xv0[j], rs, nmr), lw0[j], lb0[j]);
            v1[j] = fmaf(fmaf(xv1[j], rs, nmr), lw1[j], lb1[j]);
        }
        const bf16x8 af = pack8(v0, v1);

        f32x4 d00 = *(const f32x4*)(dwr0 + kb);
        f32x4 d01 = *(const f32x4*)(dwr0 + kb + 4);
        f32x4 d10 = *(const f32x4*)(dwr1 + kb);
        f32x4 d11 = *(const f32x4*)(dwr1 + kb + 4);
        const bf16x8 bf0 = pack8(d00, d01);
        const bf16x8 bf1 = pack8(d10, d11);

        acc0 = __builtin_amdgcn_mfma_f32_16x16x32_bf16(af, bf0, acc0, 0, 0, 0);
        acc1 = __builtin_amdgcn_mfma_f32_16x16x32_bf16(af, bf1, acc1, 0, 0, 0);
    }

    // ---------- Phase 3: bias + relu, store H (bf16) to LDS ----------
    {
        const float dbv0 = db[a0];
        const float dbv1 = db[a1];
        const int hrow = 16 * rt + 4 * g;      // D layout: row = 4*(lane>>4)+reg
#pragma unroll
        for (int r = 0; r < 4; ++r) {
            const float h0 = fmaxf(acc0[r] + dbv0, 0.f);
            const float h1 = fmaxf(acc1[r] + dbv1, 0.f);
            Hl[hrow + r][a0] = f2bf(h0);
            Hl[hrow + r][a1] = f2bf(h1);
        }
    }
    __syncthreads();

    // ---------- Phase 4: up-proj GEMM (M=32 rows, N=2048, K=64) + residual ----------
    bf16x8 A2[2][2];   // [row tile][k step]
#pragma unroll
    for (int rt2 = 0; rt2 < 2; ++rt2)
#pragma unroll
        for (int ks = 0; ks < 2; ++ks)
            A2[rt2][ks] = *(const bf16x8*)(&Hl[16 * rt2 + m][32 * ks + 8 * g]);

    const int dBase = 512 * w;     // each wave owns 512 columns of d
    for (int nt = 0; nt < 32; ++nt) {
        const int d = dBase + 16 * nt + m;
        const float* uwr = uw + (size_t)d * ADAPTER;
        f32x4 u00 = *(const f32x4*)(uwr + 8 * g);
        f32x4 u01 = *(const f32x4*)(uwr + 8 * g + 4);
        f32x4 u10 = *(const f32x4*)(uwr + 32 + 8 * g);
        f32x4 u11 = *(const f32x4*)(uwr + 32 + 8 * g + 4);
        const bf16x8 B0 = pack8(u00, u01);
        const bf16x8 B1 = pack8(u10, u11);

        f32x4 c0 = {0.f, 0.f, 0.f, 0.f};
        f32x4 c1 = {0.f, 0.f, 0.f, 0.f};
        c0 = __builtin_amdgcn_mfma_f32_16x16x32_bf16(A2[0][0], B0, c0, 0, 0, 0);
        c0 = __builtin_amdgcn_mfma_f32_16x16x32_bf16(A2[0][1], B1, c0, 0, 0, 0);
        c1 = __builtin_amdgcn_mfma_f32_16x16x32_bf16(A2[1][0], B0, c1, 0, 0, 0);
        c1 = __builtin_amdgcn_mfma_f32_16x16x32_bf16(A2[1][1], B1, c1, 0, 0, 0);

        const float ubv = ub[d];
#pragma unroll
        for (int r = 0; r < 4; ++r) {
            const int lr = 4 * g + r;
            const size_t i0 = (size_t)(rowBase + lr) * D_MODEL + d;
            out[i0] = x[i0] + c0[r] + ubv;
            const size_t i1 = (size_t)(rowBase + 16 + lr) * D_MODEL + d;
            out[i1] = x[i1] + c1[r] + ubv;
        }
    }
}

extern "C" void kernel_launch(void* const* d_in, const int* in_sizes, int n_in,
                              void* d_out, int out_size, void* d_ws, size_t ws_size,
                              hipStream_t stream) {
    const float* x   = (const float*)d_in[0];
    const float* lnw = (const float*)d_in[1];
    const float* lnb = (const float*)d_in[2];
    const float* dw  = (const float*)d_in[3];
    const float* db  = (const float*)d_in[4];
    const float* uw  = (const float*)d_in[5];
    const float* ub  = (const float*)d_in[6];
    float* out = (float*)d_out;

    dim3 grid(NROWS / RPB);   // 512 blocks
    dim3 block(THREADS);
    houlsby_fused<<<grid, block, 0, stream>>>(x, lnw, lnb, dw, db, uw, ub, out);
}

// Round 4
// 372.105 us; speedup vs baseline: 1.1073x; 1.1073x over previous
//
#include <hip/hip_runtime.h>

#define D_MODEL 2048
#define ADAPTER 64
#define RPB     16          // rows per block
#define THREADS 256
#define NROWS   16384       // 4 * 4096

typedef __attribute__((ext_vector_type(4))) float f32x4;
typedef __attribute__((ext_vector_type(8))) short bf16x8;
typedef __attribute__((ext_vector_type(4))) unsigned short u16x4;

__device__ __forceinline__ unsigned short f2bf(float f) {
    unsigned int u = __float_as_uint(f);
    u += 0x7fffu + ((u >> 16) & 1u);       // round-to-nearest-even
    return (unsigned short)(u >> 16);
}

__device__ __forceinline__ bf16x8 pack8(f32x4 a, f32x4 b) {
    bf16x8 r;
#pragma unroll
    for (int j = 0; j < 4; ++j) {
        r[j]     = (short)f2bf(a[j]);
        r[4 + j] = (short)f2bf(b[j]);
    }
    return r;
}

// ---- prep: fp32 weights -> bf16 fragments in workspace --------------------
// dw: 64*2048 = 131072 elems, uw: 2048*64 = 131072 elems. Row-major kept.
__global__ __launch_bounds__(256)
void weights_to_bf16(const float* __restrict__ dw, const float* __restrict__ uw,
                     unsigned short* __restrict__ dwb, unsigned short* __restrict__ uwb)
{
    const int i = 4 * (blockIdx.x * 256 + threadIdx.x);   // 128 blocks * 256 thr * 4
    f32x4 a = *(const f32x4*)(dw + i);
    f32x4 b = *(const f32x4*)(uw + i);
    u16x4 ra, rb;
#pragma unroll
    for (int j = 0; j < 4; ++j) { ra[j] = f2bf(a[j]); rb[j] = f2bf(b[j]); }
    *(u16x4*)(dwb + i) = ra;
    *(u16x4*)(uwb + i) = rb;
}

// ---- main fused kernel ----------------------------------------------------
__global__ __launch_bounds__(THREADS, 4)
void houlsby_fused(const float* __restrict__ x,
                   const float* __restrict__ lnw,
                   const float* __restrict__ lnb,
                   const unsigned short* __restrict__ dwb,  // bf16 [64][2048]
                   const float* __restrict__ db,            // [64]
                   const unsigned short* __restrict__ uwb,  // bf16 [2048][64]
                   const float* __restrict__ ub,            // [2048]
                   float* __restrict__ out)
{
    __shared__ float stats_mu[RPB];
    __shared__ float stats_rs[RPB];
    __shared__ __align__(16) unsigned short Hl[RPB][ADAPTER + 8];  // bf16 bits, padded

    const int tid = threadIdx.x;
    const int w   = tid >> 6;      // wave 0..3
    const int l   = tid & 63;      // lane
    const int rowBase = blockIdx.x * RPB;

    // ---------- Phase 1: LayerNorm stats (4 rows per wave, coalesced) ----------
    for (int rr = 0; rr < 4; ++rr) {
        const int row = 4 * w + rr;
        const float* xr = x + (size_t)(rowBase + row) * D_MODEL;
        float s = 0.f, sq = 0.f;
#pragma unroll
        for (int j = 0; j < 8; ++j) {
            f32x4 v = *(const f32x4*)(xr + 4 * l + 256 * j);
            s  += v.x + v.y + v.z + v.w;
            sq += v.x * v.x + v.y * v.y + v.z * v.z + v.w * v.w;
        }
#pragma unroll
        for (int off = 32; off; off >>= 1) {
            s  += __shfl_xor(s,  off, 64);
            sq += __shfl_xor(sq, off, 64);
        }
        if (l == 0) {
            const float mu  = s * (1.f / D_MODEL);
            const float var = sq * (1.f / D_MODEL) - mu * mu;
            stats_mu[row] = mu;
            stats_rs[row] = rsqrtf(var + 1e-5f);
        }
    }
    __syncthreads();

    // ---------- Phase 2: down-proj GEMM (M=16, N=64, K=2048), bf16 MFMA ----------
    // Wave w owns adapter columns [16w, 16w+16).
    const int m  = l & 15;
    const int g  = l >> 4;         // k-group

    const float mu  = stats_mu[m];
    const float rs  = stats_rs[m];
    const float nmr = -mu * rs;                // (x - mu)*rs == fma(x, rs, nmr)

    const float* xrow = x + (size_t)(rowBase + m) * D_MODEL;
    const int a0 = 16 * w + m;
    const unsigned short* dwr = dwb + a0 * D_MODEL;

    f32x4 acc = {0.f, 0.f, 0.f, 0.f};

    for (int ks = 0; ks < 64; ++ks) {
        const int kb = 32 * ks + 8 * g;
        f32x4 xv0 = *(const f32x4*)(xrow + kb);
        f32x4 xv1 = *(const f32x4*)(xrow + kb + 4);
        f32x4 lw0 = *(const f32x4*)(lnw + kb);
        f32x4 lw1 = *(const f32x4*)(lnw + kb + 4);
        f32x4 lb0 = *(const f32x4*)(lnb + kb);
        f32x4 lb1 = *(const f32x4*)(lnb + kb + 4);
        f32x4 v0, v1;
#pragma unroll
        for (int j = 0; j < 4; ++j) {
            v0[j] = fmaf(fmaf(xv0[j], rs, nmr), lw0[j], lb0[j]);
            v1[j] = fmaf(fmaf(xv1[j], rs, nmr), lw1[j], lb1[j]);
        }
        const bf16x8 af = pack8(v0, v1);
        const bf16x8 bw = *(const bf16x8*)(dwr + kb);   // 16B bf16 fragment

        acc = __builtin_amdgcn_mfma_f32_16x16x32_bf16(af, bw, acc, 0, 0, 0);
    }

    // ---------- Phase 3: bias + relu, store H (bf16) to LDS ----------
    {
        const float dbv = db[a0];
#pragma unroll
        for (int r = 0; r < 4; ++r) {
            const float h = fmaxf(acc[r] + dbv, 0.f);
            Hl[4 * g + r][a0] = f2bf(h);       // D layout: row = 4*(lane>>4)+reg
        }
    }
    __syncthreads();

    // ---------- Phase 4: up-proj GEMM (M=16, N=2048, K=64) + residual ----------
    bf16x8 A2[2];
#pragma unroll
    for (int ks = 0; ks < 2; ++ks)
        A2[ks] = *(const bf16x8*)(&Hl[m][32 * ks + 8 * g]);

    const int dBase = 512 * w;     // each wave owns 512 columns of d
    for (int nt = 0; nt < 32; ++nt) {
        const int d = dBase + 16 * nt + m;
        const unsigned short* uwr = uwb + d * ADAPTER;
        const bf16x8 B0 = *(const bf16x8*)(uwr + 8 * g);
        const bf16x8 B1 = *(const bf16x8*)(uwr + 32 + 8 * g);

        f32x4 c = {0.f, 0.f, 0.f, 0.f};
        c = __builtin_amdgcn_mfma_f32_16x16x32_bf16(A2[0], B0, c, 0, 0, 0);
        c = __builtin_amdgcn_mfma_f32_16x16x32_bf16(A2[1], B1, c, 0, 0, 0);

        const float ubv = ub[d];
#pragma unroll
        for (int r = 0; r < 4; ++r) {
            const int lr = 4 * g + r;
            const size_t i0 = (size_t)(rowBase + lr) * D_MODEL + d;
            out[i0] = x[i0] + c[r] + ubv;
        }
    }
}

extern "C" void kernel_launch(void* const* d_in, const int* in_sizes, int n_in,
                              void* d_out, int out_size, void* d_ws, size_t ws_size,
                              hipStream_t stream) {
    const float* x   = (const float*)d_in[0];
    const float* lnw = (const float*)d_in[1];
    const float* lnb = (const float*)d_in[2];
    const float* dw  = (const float*)d_in[3];
    const float* db  = (const float*)d_in[4];
    const float* uw  = (const float*)d_in[5];
    const float* ub  = (const float*)d_in[6];
    float* out = (float*)d_out;

    unsigned short* dwb = (unsigned short*)d_ws;                       // 256 KiB
    unsigned short* uwb = (unsigned short*)((char*)d_ws + 64 * 2048 * 2);

    // prep: 131072 elems / (256 thr * 4) = 128 blocks
    weights_to_bf16<<<dim3(128), dim3(256), 0, stream>>>(dw, uw, dwb, uwb);

    dim3 grid(NROWS / RPB);   // 1024 blocks = 4 per CU
    dim3 block(THREADS);
    houlsby_fused<<<grid, block, 0, stream>>>(x, lnw, lnb, dwb, db, uwb, ub, out);
}

// Round 5
// 289.074 us; speedup vs baseline: 1.4254x; 1.2872x over previous
//
#include <hip/hip_runtime.h>

#define D_MODEL 2048
#define ADAPTER 64
#define RPB     16          // rows per block
#define THREADS 256
#define NROWS   16384       // 4 * 4096

typedef __attribute__((ext_vector_type(4))) float f32x4;
typedef __attribute__((ext_vector_type(8))) short bf16x8;
typedef __attribute__((ext_vector_type(4))) unsigned short u16x4;
typedef __attribute__((ext_vector_type(8))) unsigned short u16x8;

__device__ __forceinline__ unsigned short f2bf(float f) {
    unsigned int u = __float_as_uint(f);
    u += 0x7fffu + ((u >> 16) & 1u);       // round-to-nearest-even
    return (unsigned short)(u >> 16);
}
__device__ __forceinline__ float bf2f(unsigned short u) {
    return __uint_as_float(((unsigned int)u) << 16);
}

// ---- prep: fp32 weights -> bf16 in workspace ------------------------------
__global__ __launch_bounds__(256)
void weights_to_bf16(const float* __restrict__ dw, const float* __restrict__ uw,
                     unsigned short* __restrict__ dwb, unsigned short* __restrict__ uwb)
{
    const int i = 4 * (blockIdx.x * 256 + threadIdx.x);   // 128 blocks
    f32x4 a = *(const f32x4*)(dw + i);
    f32x4 b = *(const f32x4*)(uw + i);
    u16x4 ra, rb;
#pragma unroll
    for (int j = 0; j < 4; ++j) { ra[j] = f2bf(a[j]); rb[j] = f2bf(b[j]); }
    *(u16x4*)(dwb + i) = ra;
    *(u16x4*)(uwb + i) = rb;
}

// ---- main fused kernel ----------------------------------------------------
// LDS x swizzle: byte_off ^= (row&7)<<4  (T2; keeps 8B/16B alignment classes)
__global__ __launch_bounds__(THREADS, 2)
void houlsby_fused(const float* __restrict__ x,
                   const float* __restrict__ lnw,
                   const float* __restrict__ lnb,
                   const unsigned short* __restrict__ dwb,  // bf16 [64][2048]
                   const float* __restrict__ db,            // [64]
                   const unsigned short* __restrict__ uwb,  // bf16 [2048][64]
                   const float* __restrict__ ub,            // [2048]
                   float* __restrict__ out)
{
    __shared__ __align__(16) unsigned short xl[RPB * D_MODEL];   // 64 KB raw bf16 x (swizzled)
    __shared__ __align__(16) unsigned short lwl[D_MODEL];        // 4 KB bf16 ln weight
    __shared__ __align__(16) unsigned short lbl[D_MODEL];        // 4 KB bf16 ln bias
    __shared__ float stats_mu[RPB];
    __shared__ float stats_rs[RPB];
    __shared__ __align__(16) unsigned short Hl[RPB][ADAPTER + 8];

    const int tid = threadIdx.x;
    const int w   = tid >> 6;      // wave 0..3
    const int l   = tid & 63;      // lane
    const int rowBase = blockIdx.x * RPB;

    // ---------- Pass A0: ln params -> LDS bf16 (coalesced) ----------
#pragma unroll
    for (int j = 0; j < 2; ++j) {
        const int c4 = tid + 256 * j;            // f32x4 index, col = 4*c4
        f32x4 a = *(const f32x4*)(lnw + 4 * c4);
        f32x4 b = *(const f32x4*)(lnb + 4 * c4);
        u16x4 ra, rb;
#pragma unroll
        for (int k = 0; k < 4; ++k) { ra[k] = f2bf(a[k]); rb[k] = f2bf(b[k]); }
        *(u16x4*)(lwl + 4 * c4) = ra;
        *(u16x4*)(lbl + 4 * c4) = rb;
    }

    // ---------- Pass A: stream x once: stats + bf16 x -> swizzled LDS ----------
    for (int rr = 0; rr < 4; ++rr) {
        const int row = 4 * w + rr;
        const float* xr = x + (size_t)(rowBase + row) * D_MODEL;
        char* xrow_l = (char*)(xl + row * D_MODEL);
        const int swz = (row & 7) << 4;
        float s = 0.f, sq = 0.f;
#pragma unroll
        for (int j = 0; j < 8; ++j) {
            f32x4 v = *(const f32x4*)(xr + 4 * l + 256 * j);
            s  += v.x + v.y + v.z + v.w;
            sq += v.x * v.x + v.y * v.y + v.z * v.z + v.w * v.w;
            u16x4 hv;
#pragma unroll
            for (int k = 0; k < 4; ++k) hv[k] = f2bf(v[k]);
            const int boff = ((4 * l + 256 * j) * 2) ^ swz;
            *(u16x4*)(xrow_l + boff) = hv;
        }
#pragma unroll
        for (int off = 32; off; off >>= 1) {
            s  += __shfl_xor(s,  off, 64);
            sq += __shfl_xor(sq, off, 64);
        }
        if (l == 0) {
            const float mu  = s * (1.f / D_MODEL);
            const float var = sq * (1.f / D_MODEL) - mu * mu;
            stats_mu[row] = mu;
            stats_rs[row] = rsqrtf(var + 1e-5f);
        }
    }
    __syncthreads();

    // ---------- Phase 2: down-proj GEMM (M=16, N=64, K=2048) ----------
    const int m  = l & 15;
    const int g  = l >> 4;

    const float mu  = stats_mu[m];
    const float rs  = stats_rs[m];
    const float nmr = -mu * rs;

    const int a0 = 16 * w + m;
    const unsigned short* dwr = dwb + a0 * D_MODEL;
    const char* xrow_l = (const char*)(xl + m * D_MODEL);
    const int swzm = (m & 7) << 4;

    f32x4 acc = {0.f, 0.f, 0.f, 0.f};

#pragma unroll 4
    for (int ks = 0; ks < 64; ++ks) {
        const int kb = 32 * ks + 8 * g;                       // k element index
        u16x8 xv = *(const u16x8*)(xrow_l + ((2 * kb) ^ swzm));  // raw bf16 x
        u16x8 lwv = *(const u16x8*)(lwl + kb);                // broadcast reads
        u16x8 lbv = *(const u16x8*)(lbl + kb);
        bf16x8 af;
#pragma unroll
        for (int jj = 0; jj < 8; ++jj) {
            const float xf = bf2f(xv[jj]);
            const float v  = fmaf(fmaf(xf, rs, nmr), bf2f(lwv[jj]), bf2f(lbv[jj]));
            af[jj] = (short)f2bf(v);
        }
        const bf16x8 bw = *(const bf16x8*)(dwr + kb);          // L2-hot stream
        acc = __builtin_amdgcn_mfma_f32_16x16x32_bf16(af, bw, acc, 0, 0, 0);
    }

    // ---------- Phase 3: bias + relu -> H (bf16) in LDS ----------
    {
        const float dbv = db[a0];
#pragma unroll
        for (int r = 0; r < 4; ++r) {
            const float h = fmaxf(acc[r] + dbv, 0.f);
            Hl[4 * g + r][a0] = f2bf(h);       // D layout: row = 4*(lane>>4)+reg
        }
    }
    __syncthreads();

    // ---------- Phase 4: up-proj, operand-swapped (A=uw, B=H) + residual ----------
    // D[m',n] = sum_a UW[d_{m'},a] H[row_n,a]; lane holds O[row m][d0+4g+r]
    bf16x8 Hf[2];
#pragma unroll
    for (int ks = 0; ks < 2; ++ks)
        Hf[ks] = *(const bf16x8*)(&Hl[m][32 * ks + 8 * g]);

    const int dBase = 512 * w;
    const size_t orow = (size_t)(rowBase + m) * D_MODEL;
#pragma unroll 2
    for (int nt = 0; nt < 32; ++nt) {
        const int d0 = dBase + 16 * nt;
        const unsigned short* uwr = uwb + (d0 + m) * ADAPTER;
        const bf16x8 A0 = *(const bf16x8*)(uwr + 8 * g);
        const bf16x8 A1 = *(const bf16x8*)(uwr + 32 + 8 * g);

        f32x4 c = {0.f, 0.f, 0.f, 0.f};
        c = __builtin_amdgcn_mfma_f32_16x16x32_bf16(A0, Hf[0], c, 0, 0, 0);
        c = __builtin_amdgcn_mfma_f32_16x16x32_bf16(A1, Hf[1], c, 0, 0, 0);

        const int dcol = d0 + 4 * g;
        const f32x4 ubv = *(const f32x4*)(ub + dcol);
        const u16x4 xres = *(const u16x4*)(xrow_l + ((2 * dcol) ^ swzm));
        f32x4 o;
#pragma unroll
        for (int r = 0; r < 4; ++r)
            o[r] = bf2f(xres[r]) + c[r] + ubv[r];
        *(f32x4*)(out + orow + dcol) = o;
    }
}

extern "C" void kernel_launch(void* const* d_in, const int* in_sizes, int n_in,
                              void* d_out, int out_size, void* d_ws, size_t ws_size,
                              hipStream_t stream) {
    const float* x   = (const float*)d_in[0];
    const float* lnw = (const float*)d_in[1];
    const float* lnb = (const float*)d_in[2];
    const float* dw  = (const float*)d_in[3];
    const float* db  = (const float*)d_in[4];
    const float* uw  = (const float*)d_in[5];
    const float* ub  = (const float*)d_in[6];
    float* out = (float*)d_out;

    unsigned short* dwb = (unsigned short*)d_ws;                       // 256 KiB
    unsigned short* uwb = (unsigned short*)((char*)d_ws + 64 * 2048 * 2);

    weights_to_bf16<<<dim3(128), dim3(256), 0, stream>>>(dw, uw, dwb, uwb);

    dim3 grid(NROWS / RPB);   // 1024 blocks
    dim3 block(THREADS);
    houlsby_fused<<<grid, block, 0, stream>>>(x, lnw, lnb, dwb, db, uwb, ub, out);
}